// Round 6
// baseline (362.412 us; speedup 1.0000x reference)
//
#include <hip/hip_runtime.h>
#include <hip/hip_bf16.h>
#include <stdint.h>
#include <stddef.h>

// Problem constants (fixed by the reference)
#define B_ 4
#define N_ 2048
#define E_ 1024
#define H_ 16
#define D_ 64
// SCALE = 1/sqrt(64) = 0.125 exactly (applied by pre-scaling Q, exact in bf16)

using bf16 = __hip_bfloat16;
typedef __bf16 bf16x8 __attribute__((ext_vector_type(8)));   // 4 VGPRs, MFMA A/B frag
typedef float  f32x4  __attribute__((ext_vector_type(4)));
typedef float  f32x16 __attribute__((ext_vector_type(16)));  // MFMA C/D frag (32x32)
typedef unsigned int u32x2 __attribute__((ext_vector_type(2)));

// ---- dtype helpers --------------------------------------------------------
__device__ inline bf16x8 load8(const float* p) {
    f32x4 a = *(const f32x4*)p;
    f32x4 b = *(const f32x4*)(p + 4);
    bf16x8 r;
#pragma unroll
    for (int e = 0; e < 4; e++) { r[e] = (__bf16)a[e]; r[e + 4] = (__bf16)b[e]; }
    return r;
}
__device__ inline void store_elem(float* C, size_t idx, float v) { C[idx] = v; }
__device__ inline void store_elem(bf16* C, size_t idx, float v) {
    C[idx] = __float2bfloat16(v);
}

// Async global->LDS, 16 B per lane (LDS dest = wave-uniform base + lane*16).
__device__ inline void async_stage16(const bf16* g, bf16* l) {
    __builtin_amdgcn_global_load_lds(
        (const __attribute__((address_space(1))) uint32_t*)g,
        (__attribute__((address_space(3))) uint32_t*)l, 16, 0, 0);
}
__device__ inline void manual_stage16(const float* g, bf16* l) {
    *(bf16x8*)l = load8(g);
}

// ---------------------------------------------------------------------------
// fp32 -> bf16 convert. Blocks 0..2047: weights (512 each); blocks
// 2048..14335: the 3 inputs (4096 each).
// ---------------------------------------------------------------------------
__global__ __launch_bounds__(256) void cvt_all(
    const float* __restrict__ w0, const float* __restrict__ w1,
    const float* __restrict__ w2, const float* __restrict__ w3,
    bf16* __restrict__ wd,
    const float* __restrict__ x0, const float* __restrict__ x1,
    const float* __restrict__ x2,
    bf16* __restrict__ xd0, bf16* __restrict__ xd1, bf16* __restrict__ xd2)
{
    int bx = blockIdx.x;
    const float* s; bf16* d;
    if (bx < 2048) {
        const int seg = bx >> 9;
        s = seg == 0 ? w0 : seg == 1 ? w1 : seg == 2 ? w2 : w3;
        d = wd + (size_t)seg * (E_ * E_);
        bx &= 511;
    } else {
        bx -= 2048;
        const int seg = bx >> 12;
        s = seg == 0 ? x0 : seg == 1 ? x1 : x2;
        d = seg == 0 ? xd0 : seg == 1 ? xd1 : xd2;
        bx &= 4095;
    }
    const size_t off = ((size_t)bx * 256 + threadIdx.x) * 8;
    *(bf16x8*)&d[off] = load8(s + off);
}

// ---------------------------------------------------------------------------
// GEMM: C[M,E] = A[M,E] @ W[E,E]^T (+ optional fp32 bias), fp32 accumulate,
// v_mfma_f32_16x16x32_bf16, 128x128 tile, BK=32, 4 waves; batched blockIdx.z.
// ---------------------------------------------------------------------------
struct GemmB { const void* A[3]; void* C[3]; };

template <typename TA, typename TC>
__global__ __launch_bounds__(256) void gemm_bt(
    GemmB batch, const bf16* __restrict__ Wb, const float* __restrict__ bias)
{
    __shared__ bf16 As[128 * 32];
    __shared__ bf16 Bs[128 * 32];

    const TA*   __restrict__ A = (const TA*)batch.A[blockIdx.z];
    TC*         __restrict__ C = (TC*)batch.C[blockIdx.z];
    const bf16* __restrict__ W = Wb + (size_t)blockIdx.z * (E_ * E_);

    const int tid  = threadIdx.x;
    const int lane = tid & 63;
    const int wave = tid >> 6;
    const int wr   = wave >> 1;
    const int wc   = wave & 1;
    const int r    = lane & 15;
    const int quad = lane >> 4;

    const int m0 = blockIdx.y * 128;
    const int n0 = blockIdx.x * 128;

    const int row0 = tid >> 2,         cc0 = (tid & 3) * 8;
    const int row1 = (tid + 256) >> 2, cc1 = cc0;

    f32x4 acc[4][4];
#pragma unroll
    for (int i = 0; i < 4; i++)
#pragma unroll
        for (int j = 0; j < 4; j++)
            acc[i][j] = {0.0f, 0.0f, 0.0f, 0.0f};

    for (int k0 = 0; k0 < E_; k0 += 32) {
        __syncthreads();
        if constexpr (__is_same(TA, bf16)) {
            async_stage16(&A[(size_t)(m0 + row0) * E_ + k0 + cc0], &As[tid * 8]);
            async_stage16(&A[(size_t)(m0 + row1) * E_ + k0 + cc1], &As[(tid + 256) * 8]);
        } else {
            manual_stage16(&A[(size_t)(m0 + row0) * E_ + k0 + cc0], &As[tid * 8]);
            manual_stage16(&A[(size_t)(m0 + row1) * E_ + k0 + cc1], &As[(tid + 256) * 8]);
        }
        async_stage16(&W[(size_t)(n0 + row0) * E_ + k0 + cc0], &Bs[tid * 8]);
        async_stage16(&W[(size_t)(n0 + row1) * E_ + k0 + cc1], &Bs[(tid + 256) * 8]);
        __syncthreads();

        bf16x8 a[4], b[4];
#pragma unroll
        for (int mt = 0; mt < 4; mt++)
            a[mt] = *(const bf16x8*)&As[(wr * 64 + mt * 16 + r) * 32 + quad * 8];
#pragma unroll
        for (int nt = 0; nt < 4; nt++)
            b[nt] = *(const bf16x8*)&Bs[(wc * 64 + nt * 16 + r) * 32 + quad * 8];
#pragma unroll
        for (int mt = 0; mt < 4; mt++)
#pragma unroll
            for (int nt = 0; nt < 4; nt++)
                acc[mt][nt] = __builtin_amdgcn_mfma_f32_16x16x32_bf16(
                    a[mt], b[nt], acc[mt][nt], 0, 0, 0);
    }

#pragma unroll
    for (int mt = 0; mt < 4; mt++) {
#pragma unroll
        for (int nt = 0; nt < 4; nt++) {
            const int col = n0 + wc * 64 + nt * 16 + r;
            float bv = bias ? bias[col] : 0.0f;
#pragma unroll
            for (int rg = 0; rg < 4; rg++) {
                const int row = m0 + wr * 64 + mt * 16 + quad * 4 + rg;
                store_elem(C, (size_t)row * E_ + col, acc[mt][nt][rg] + bv);
            }
        }
    }
}

// ===========================================================================
// Flash attention, round-12: SPLIT-K (flash-decode) to flatten makespan.
//
// Evidence: T_tile ~= 3.0-3.2 us invariant across rounds 6-11 (inner-loop
// rewrites, L2 fix, occupancy fix all left it unchanged); wall time ==
// longest-block-tiles x T_tile (r11: 32 x 3.07 = 98.2us, measured). The
// kernel is a latency-bound serial chain; only the mapping can shrink it.
//
// Round-12: chunk every (b,h,strip) into <=8 key-tile chunks -> 2560 blocks
// of 2..8 tiles. Per-CU work stays 68 tiles but concurrency stays ~4
// blocks/CU (LDS-limited) to the tail: bound ~= 68/4 x 3.07 + overhead.
// Partials: O/l in bf16 (bounded like final O) + (m,l) f32, in the xb
// region (free after proj GEMM). Combine pass merges <=4 chunks/strip.
// Inner tile body = round-8/11 verbatim. Chunk layout guarantees: every
// chunk >=2 tiles; causal mask confined to last chunk (t >= nt-2); every
// chunk has >=1 unmasked key per row (last chunk starts at tile <= 2s).
//
//   chunks/strip: s<4:1  s<8:2  s<12:3  s>=16? s<16:4   (40 per bh)
//   cid base    : s      4+2(s-4) 12+3(s-8)   24+4(s-12)
// ===========================================================================
__device__ inline void cid_to_sc(int cid, int& s, int& c) {
    if (cid < 4)       { s = cid;                 c = 0; }
    else if (cid < 12) { s = 4 + ((cid - 4) >> 1);  c = (cid - 4) & 1; }
    else if (cid < 24) { s = 8 + (cid - 12) / 3;    c = (cid - 12) % 3; }
    else               { s = 12 + ((cid - 24) >> 2); c = (cid - 24) & 3; }
}
__device__ inline int cid_base(int s) {
    return s < 4 ? s : s < 8 ? 4 + 2 * (s - 4)
         : s < 12 ? 12 + 3 * (s - 8) : 24 + 4 * (s - 12);
}
__device__ inline int n_chunks(int s) {
    return s < 4 ? 1 : s < 8 ? 2 : s < 12 ? 3 : 4;
}

__global__ __launch_bounds__(256) void attn_part(
    const bf16* __restrict__ q, const bf16* __restrict__ k,
    const bf16* __restrict__ v, bf16* __restrict__ op,
    float2* __restrict__ ml)
{
    constexpr int LS = 72;
    constexpr float LOG2E = 1.44269504088896340736f;
    __shared__ bf16 Ks[2][64 * LS];   // [buf][key][d]
    __shared__ bf16 Vt[2][64 * LS];   // [buf][d][key]

    const int tid  = threadIdx.x;
    const int lane = tid & 63;
    const int wave = tid >> 6;
    const int l31  = lane & 31;
    const int hi   = lane >> 5;

    // mapping: all chunks of a bh on one XCD (bh%8 == l%8)
    const int l     = blockIdx.x;        // 0..2559
    const int xcd   = l & 7;
    const int idx   = l >> 3;            // 0..319
    const int bh_hi = idx & 7;
    const int cid   = idx >> 3;          // 0..39
    const int bh    = (bh_hi << 3) | xcd;
    const int b     = bh >> 4;
    const int h     = bh & 15;
    int s, c;
    cid_to_sc(cid, s, c);
    const int g  = bh * 40 + cid;        // partial slot

    const int q0      = s * 128;
    const int nt_glob = 2 * s + 2;
    const int t0      = c * 8;
    const int t1      = min(t0 + 8, nt_glob);   // chunk size 2..8 tiles

    const size_t basek = (size_t)b * N_ * E_ + (size_t)h * D_;

    // staging addressing
    const int key0 = tid >> 3;        // 0..31
    const int key1 = key0 + 32;
    const int ck   = (tid & 7) * 8;
    const int kp   = tid & 31;
    const int cv   = (tid >> 5) * 8;

    // Q as B-operand of 32x32x16, pre-scaled by 0.125 (exact in bf16).
    bf16x8 qB[4];
    {
        const size_t qoff =
            ((size_t)b * N_ + q0 + wave * 32 + l31) * E_ + h * D_ + hi * 8;
#pragma unroll
        for (int kc = 0; kc < 4; kc++) {
            qB[kc] = *(const bf16x8*)&q[qoff + kc * 16];
#pragma unroll
            for (int e = 0; e < 8; e++)
                qB[kc][e] = (__bf16)((float)qB[kc][e] * 0.125f);
        }
    }

    float m_i = -1e30f;
    float l_i = 0.0f;
    f32x16 o_acc[2];
#pragma unroll
    for (int rg = 0; rg < 16; rg++) { o_acc[0][rg] = 0.0f; o_acc[1][rg] = 0.0f; }

    // ---- prologue: tile t0 -> buf0; issue loads for tile t0+1 ----
    bf16x8 kp0, kp1, vp0, vp1;
    kp0 = *(const bf16x8*)&k[basek + ((size_t)t0 * 64 + key0) * E_ + ck];
    kp1 = *(const bf16x8*)&k[basek + ((size_t)t0 * 64 + key1) * E_ + ck];
    vp0 = *(const bf16x8*)&v[basek + ((size_t)t0 * 64 + 2 * kp) * E_ + cv];
    vp1 = *(const bf16x8*)&v[basek + ((size_t)t0 * 64 + 2 * kp + 1) * E_ + cv];
    *(bf16x8*)&Ks[0][key0 * LS + ck] = kp0;
    *(bf16x8*)&Ks[0][key1 * LS + ck] = kp1;
#pragma unroll
    for (int e = 0; e < 8; e++) {
        union { __bf16 hh[2]; uint32_t u; } pk;
        pk.hh[0] = vp0[e]; pk.hh[1] = vp1[e];
        *(uint32_t*)&Vt[0][(cv + e) * LS + 2 * kp] = pk.u;
    }
    {
        const size_t j1 = (size_t)(t0 + 1) * 64;   // chunk size >= 2 always
        kp0 = *(const bf16x8*)&k[basek + (j1 + key0) * E_ + ck];
        kp1 = *(const bf16x8*)&k[basek + (j1 + key1) * E_ + ck];
        vp0 = *(const bf16x8*)&v[basek + (j1 + 2 * kp) * E_ + cv];
        vp1 = *(const bf16x8*)&v[basek + (j1 + 2 * kp + 1) * E_ + cv];
    }
    __syncthreads();              // buf0 visible to all waves

    for (int t = t0; t < t1; t++) {
        const int cur = (t - t0) & 1;

        // ---- commit tile t+1 (regs loaded one tile ago) to other buf ----
        if (t + 1 < t1) {
            *(bf16x8*)&Ks[cur ^ 1][key0 * LS + ck] = kp0;
            *(bf16x8*)&Ks[cur ^ 1][key1 * LS + ck] = kp1;
#pragma unroll
            for (int e = 0; e < 8; e++) {
                union { __bf16 hh[2]; uint32_t u; } pk;
                pk.hh[0] = vp0[e]; pk.hh[1] = vp1[e];
                *(uint32_t*)&Vt[cur ^ 1][(cv + e) * LS + 2 * kp] = pk.u;
            }
        }
        // ---- issue loads for tile t+2 ----
        if (t + 2 < t1) {
            const size_t j2 = (size_t)(t + 2) * 64;
            kp0 = *(const bf16x8*)&k[basek + (j2 + key0) * E_ + ck];
            kp1 = *(const bf16x8*)&k[basek + (j2 + key1) * E_ + ck];
            vp0 = *(const bf16x8*)&v[basek + (j2 + 2 * kp) * E_ + cv];
            vp1 = *(const bf16x8*)&v[basek + (j2 + 2 * kp + 1) * E_ + cv];
        }

        // ---- S^T[key][qrow] = K·(scaled Q)^T : 8 MFMA 32x32x16 ----
        f32x16 sf[2];
#pragma unroll
        for (int rg = 0; rg < 16; rg++) { sf[0][rg] = 0.0f; sf[1][rg] = 0.0f; }
#pragma unroll
        for (int kc = 0; kc < 4; kc++) {
            bf16x8 ka0 = *(const bf16x8*)&Ks[cur][l31 * LS + kc * 16 + hi * 8];
            bf16x8 ka1 = *(const bf16x8*)&Ks[cur][(32 + l31) * LS + kc * 16 + hi * 8];
            sf[0] = __builtin_amdgcn_mfma_f32_32x32x16_bf16(ka0, qB[kc], sf[0], 0, 0, 0);
            sf[1] = __builtin_amdgcn_mfma_f32_32x32x16_bf16(ka1, qB[kc], sf[1], 0, 0, 0);
        }

        // ---- causal mask (only last 2 tiles of the strip = last chunk) ----
        if (t >= nt_glob - 2) {
            const int qgl   = q0 + wave * 32 + l31;
            const int kbase = t * 64 + 4 * hi;
#pragma unroll
            for (int mt = 0; mt < 2; mt++)
#pragma unroll
                for (int rg = 0; rg < 16; rg++) {
                    const int kgl = kbase + mt * 32 + (rg & 3) + 8 * (rg >> 2);
                    if (kgl > qgl) sf[mt][rg] = -1e30f;
                }
        }

        // ---- online softmax ----
        float mhalf[8];
#pragma unroll
        for (int i = 0; i < 8; i++)
            mhalf[i] = fmaxf(fmaxf(sf[0][2 * i], sf[0][2 * i + 1]),
                             fmaxf(sf[1][2 * i], sf[1][2 * i + 1]));
        float mx = fmaxf(fmaxf(fmaxf(mhalf[0], mhalf[1]), fmaxf(mhalf[2], mhalf[3])),
                         fmaxf(fmaxf(mhalf[4], mhalf[5]), fmaxf(mhalf[6], mhalf[7])));
        mx = fmaxf(mx, __shfl_xor(mx, 32));

        if (!__all(mx <= m_i + 8.0f)) {
            const float m_new = fmaxf(m_i, mx);
            const float al = exp2f((m_i - m_new) * LOG2E);
            l_i *= al;
#pragma unroll
            for (int mo = 0; mo < 2; mo++)
#pragma unroll
                for (int rg = 0; rg < 16; rg++) o_acc[mo][rg] *= al;
            m_i = m_new;
        }

        const float m2 = m_i * LOG2E;
#pragma unroll
        for (int mt = 0; mt < 2; mt++)
#pragma unroll
            for (int rg = 0; rg < 16; rg++)
                sf[mt][rg] = exp2f(__builtin_fmaf(sf[mt][rg], LOG2E, -m2));

        float ls = 0.0f;
#pragma unroll
        for (int mt = 0; mt < 2; mt++) {
            const float a0 = (sf[mt][0] + sf[mt][1]) + (sf[mt][2] + sf[mt][3]);
            const float a1 = (sf[mt][4] + sf[mt][5]) + (sf[mt][6] + sf[mt][7]);
            const float a2 = (sf[mt][8] + sf[mt][9]) + (sf[mt][10] + sf[mt][11]);
            const float a3 = (sf[mt][12] + sf[mt][13]) + (sf[mt][14] + sf[mt][15]);
            ls += (a0 + a1) + (a2 + a3);
        }
        ls += __shfl_xor(ls, 32);
        l_i += ls;

        // ---- pack P to bf16 pair-words ----
        uint32_t w[2][8];
#pragma unroll
        for (int mt = 0; mt < 2; mt++)
#pragma unroll
            for (int i = 0; i < 8; i++) {
                union { __bf16 hh[2]; uint32_t u; } pk;
                pk.hh[0] = (__bf16)sf[mt][2 * i];
                pk.hh[1] = (__bf16)sf[mt][2 * i + 1];
                w[mt][i] = pk.u;
            }

        // ---- O^T += V^T · P^T : PV B-frags via permlane32_swap ----
#pragma unroll
        for (int ks = 0; ks < 4; ks++) {
            const int cc = 4 * (ks & 1);
            const int mt = ks >> 1;
            u32x2 r1 = __builtin_amdgcn_permlane32_swap(
                w[mt][cc + 0], w[mt][cc + 2], false, false);
            u32x2 r2 = __builtin_amdgcn_permlane32_swap(
                w[mt][cc + 1], w[mt][cc + 3], false, false);
            union { uint32_t u[4]; bf16x8 v8; } pbu;
            pbu.u[0] = r1[0]; pbu.u[1] = r2[0];
            pbu.u[2] = r1[1]; pbu.u[3] = r2[1];
#pragma unroll
            for (int mo = 0; mo < 2; mo++) {
                bf16x8 va = *(const bf16x8*)
                    &Vt[cur][(mo * 32 + l31) * LS + ks * 16 + hi * 8];
                o_acc[mo] = __builtin_amdgcn_mfma_f32_32x32x16_bf16(
                    va, pbu.v8, o_acc[mo], 0, 0, 0);
            }
        }

        __syncthreads();
    }

    // ---- write partial: op[g][row][d] = O/l (bf16), ml[g][row] = (m,l) ----
    {
        const int row = wave * 32 + l31;
        const float invl = 1.0f / l_i;
        const size_t obase = (size_t)g * 8192 + (size_t)row * 64;
#pragma unroll
        for (int mo = 0; mo < 2; mo++)
#pragma unroll
            for (int gq = 0; gq < 4; gq++) {
                union { __bf16 hh[4]; uint2 u2; } pk;
#pragma unroll
                for (int jj = 0; jj < 4; jj++)
                    pk.hh[jj] = (__bf16)(o_acc[mo][4 * gq + jj] * invl);
                *(uint2*)&op[obase + mo * 32 + 8 * gq + 4 * hi] = pk.u2;
            }
        if (hi == 0)
            ml[((size_t)g << 7) + row] = make_float2(m_i, l_i);
    }
}

// Combine: one block per (bh, strip); merge <=4 chunk partials.
__global__ __launch_bounds__(256) void attn_comb(
    const bf16* __restrict__ op, const float2* __restrict__ ml,
    bf16* __restrict__ o)
{
    constexpr float LOG2E = 1.44269504088896340736f;
    const int bid = blockIdx.x;          // 0..1023
    const int bh  = bid >> 4;
    const int s   = bid & 15;
    const int b   = bh >> 4;
    const int h   = bh & 15;
    const int gb  = bh * 40 + cid_base(s);
    const int nc  = n_chunks(s);

    const int tid = threadIdx.x;
    const int row = tid >> 1;            // 0..127
    const int dof = (tid & 1) * 32;

    float mv[4], lv[4];
#pragma unroll
    for (int c = 0; c < 4; c++)
        if (c < nc) {
            float2 t = ml[((size_t)(gb + c) << 7) + row];
            mv[c] = t.x; lv[c] = t.y;
        }
    float M = -1e30f;
#pragma unroll
    for (int c = 0; c < 4; c++) if (c < nc) M = fmaxf(M, mv[c]);
    float wt[4]; float L = 0.0f;
#pragma unroll
    for (int c = 0; c < 4; c++)
        if (c < nc) { wt[c] = lv[c] * exp2f((mv[c] - M) * LOG2E); L += wt[c]; }
    const float invL = 1.0f / L;

    float acc[32];
#pragma unroll
    for (int e = 0; e < 32; e++) acc[e] = 0.0f;
#pragma unroll
    for (int c = 0; c < 4; c++)
        if (c < nc) {
            const float wc = wt[c];
            const size_t base = (size_t)(gb + c) * 8192 + (size_t)row * 64 + dof;
#pragma unroll
            for (int seg = 0; seg < 4; seg++) {
                bf16x8 v8 = *(const bf16x8*)&op[base + seg * 8];
#pragma unroll
                for (int e = 0; e < 8; e++)
                    acc[seg * 8 + e] = __builtin_fmaf(wc, (float)v8[e], acc[seg * 8 + e]);
            }
        }

    const size_t obase = ((size_t)b * N_ + s * 128 + row) * E_ + h * D_ + dof;
#pragma unroll
    for (int seg = 0; seg < 4; seg++) {
        bf16x8 v8;
#pragma unroll
        for (int e = 0; e < 8; e++)
            v8[e] = (__bf16)(acc[seg * 8 + e] * invL);
        *(bf16x8*)&o[obase + seg * 8] = v8;
    }
}

// ---------------------------------------------------------------------------
// Fallback single-pass attention (round-11), used when ws too small for
// partials. Grid 1024, balanced strip mapping.
// ---------------------------------------------------------------------------
__global__ __launch_bounds__(256) void attn_fwd(
    const bf16* __restrict__ q, const bf16* __restrict__ k,
    const bf16* __restrict__ v, bf16* __restrict__ o)
{
    constexpr int LS = 72;
    constexpr float LOG2E = 1.44269504088896340736f;
    __shared__ bf16 Ks[2][64 * LS];
    __shared__ bf16 Vt[2][64 * LS];

    const int tid  = threadIdx.x;
    const int lane = tid & 63;
    const int wave = tid >> 6;
    const int l31  = lane & 31;
    const int hi   = lane >> 5;

    const int l    = blockIdx.x;
    const int xcd  = l & 7;
    const int j    = l >> 3;
    const int bh_hi= j & 7;
    const int a    = (j >> 3) & 3;
    const int slot = j >> 5;
    const int s    = 4 * slot + (a ^ slot);
    const int bh   = (bh_hi << 3) | xcd;
    const int b    = bh >> 4;
    const int h    = bh & 15;

    const size_t basek = (size_t)b * N_ * E_ + (size_t)h * D_;

    const int key0 = tid >> 3;
    const int key1 = key0 + 32;
    const int ck   = (tid & 7) * 8;
    const int kp   = tid & 31;
    const int cv   = (tid >> 5) * 8;

    const int q0 = s * 128;
    const int nt = 2 * s + 2;

    bf16x8 qB[4];
    {
        const size_t qoff =
            ((size_t)b * N_ + q0 + wave * 32 + l31) * E_ + h * D_ + hi * 8;
#pragma unroll
        for (int kc = 0; kc < 4; kc++) {
            qB[kc] = *(const bf16x8*)&q[qoff + kc * 16];
#pragma unroll
            for (int e = 0; e < 8; e++)
                qB[kc][e] = (__bf16)((float)qB[kc][e] * 0.125f);
        }
    }

    float m_i = -1e30f;
    float l_i = 0.0f;
    f32x16 o_acc[2];
#pragma unroll
    for (int rg = 0; rg < 16; rg++) { o_acc[0][rg] = 0.0f; o_acc[1][rg] = 0.0f; }

    bf16x8 kp0, kp1, vp0, vp1;
    kp0 = *(const bf16x8*)&k[basek + (size_t)key0 * E_ + ck];
    kp1 = *(const bf16x8*)&k[basek + (size_t)key1 * E_ + ck];
    vp0 = *(const bf16x8*)&v[basek + (size_t)(2 * kp) * E_ + cv];
    vp1 = *(const bf16x8*)&v[basek + (size_t)(2 * kp + 1) * E_ + cv];
    *(bf16x8*)&Ks[0][key0 * LS + ck] = kp0;
    *(bf16x8*)&Ks[0][key1 * LS + ck] = kp1;
#pragma unroll
    for (int e = 0; e < 8; e++) {
        union { __bf16 hh[2]; uint32_t u; } pk;
        pk.hh[0] = vp0[e]; pk.hh[1] = vp1[e];
        *(uint32_t*)&Vt[0][(cv + e) * LS + 2 * kp] = pk.u;
    }
    {
        const size_t j1 = 64;
        kp0 = *(const bf16x8*)&k[basek + (j1 + key0) * E_ + ck];
        kp1 = *(const bf16x8*)&k[basek + (j1 + key1) * E_ + ck];
        vp0 = *(const bf16x8*)&v[basek + (j1 + 2 * kp) * E_ + cv];
        vp1 = *(const bf16x8*)&v[basek + (j1 + 2 * kp + 1) * E_ + cv];
    }
    __syncthreads();

    for (int t = 0; t < nt; t++) {
        const int cur = t & 1;
        if (t + 1 < nt) {
            *(bf16x8*)&Ks[cur ^ 1][key0 * LS + ck] = kp0;
            *(bf16x8*)&Ks[cur ^ 1][key1 * LS + ck] = kp1;
#pragma unroll
            for (int e = 0; e < 8; e++) {
                union { __bf16 hh[2]; uint32_t u; } pk;
                pk.hh[0] = vp0[e]; pk.hh[1] = vp1[e];
                *(uint32_t*)&Vt[cur ^ 1][(cv + e) * LS + 2 * kp] = pk.u;
            }
        }
        if (t + 2 < nt) {
            const size_t j2 = (size_t)(t + 2) * 64;
            kp0 = *(const bf16x8*)&k[basek + (j2 + key0) * E_ + ck];
            kp1 = *(const bf16x8*)&k[basek + (j2 + key1) * E_ + ck];
            vp0 = *(const bf16x8*)&v[basek + (j2 + 2 * kp) * E_ + cv];
            vp1 = *(const bf16x8*)&v[basek + (j2 + 2 * kp + 1) * E_ + cv];
        }

        f32x16 sf[2];
#pragma unroll
        for (int rg = 0; rg < 16; rg++) { sf[0][rg] = 0.0f; sf[1][rg] = 0.0f; }
#pragma unroll
        for (int kc = 0; kc < 4; kc++) {
            bf16x8 ka0 = *(const bf16x8*)&Ks[cur][l31 * LS + kc * 16 + hi * 8];
            bf16x8 ka1 = *(const bf16x8*)&Ks[cur][(32 + l31) * LS + kc * 16 + hi * 8];
            sf[0] = __builtin_amdgcn_mfma_f32_32x32x16_bf16(ka0, qB[kc], sf[0], 0, 0, 0);
            sf[1] = __builtin_amdgcn_mfma_f32_32x32x16_bf16(ka1, qB[kc], sf[1], 0, 0, 0);
        }

        if (t >= nt - 2) {
            const int qgl   = q0 + wave * 32 + l31;
            const int kbase = t * 64 + 4 * hi;
#pragma unroll
            for (int mt = 0; mt < 2; mt++)
#pragma unroll
                for (int rg = 0; rg < 16; rg++) {
                    const int kgl = kbase + mt * 32 + (rg & 3) + 8 * (rg >> 2);
                    if (kgl > qgl) sf[mt][rg] = -1e30f;
                }
        }

        float mhalf[8];
#pragma unroll
        for (int i = 0; i < 8; i++)
            mhalf[i] = fmaxf(fmaxf(sf[0][2 * i], sf[0][2 * i + 1]),
                             fmaxf(sf[1][2 * i], sf[1][2 * i + 1]));
        float mx = fmaxf(fmaxf(fmaxf(mhalf[0], mhalf[1]), fmaxf(mhalf[2], mhalf[3])),
                         fmaxf(fmaxf(mhalf[4], mhalf[5]), fmaxf(mhalf[6], mhalf[7])));
        mx = fmaxf(mx, __shfl_xor(mx, 32));

        if (!__all(mx <= m_i + 8.0f)) {
            const float m_new = fmaxf(m_i, mx);
            const float al = exp2f((m_i - m_new) * LOG2E);
            l_i *= al;
#pragma unroll
            for (int mo = 0; mo < 2; mo++)
#pragma unroll
                for (int rg = 0; rg < 16; rg++) o_acc[mo][rg] *= al;
            m_i = m_new;
        }

        const float m2 = m_i * LOG2E;
#pragma unroll
        for (int mt = 0; mt < 2; mt++)
#pragma unroll
            for (int rg = 0; rg < 16; rg++)
                sf[mt][rg] = exp2f(__builtin_fmaf(sf[mt][rg], LOG2E, -m2));

        float ls = 0.0f;
#pragma unroll
        for (int mt = 0; mt < 2; mt++) {
            const float a0 = (sf[mt][0] + sf[mt][1]) + (sf[mt][2] + sf[mt][3]);
            const float a1 = (sf[mt][4] + sf[mt][5]) + (sf[mt][6] + sf[mt][7]);
            const float a2 = (sf[mt][8] + sf[mt][9]) + (sf[mt][10] + sf[mt][11]);
            const float a3 = (sf[mt][12] + sf[mt][13]) + (sf[mt][14] + sf[mt][15]);
            ls += (a0 + a1) + (a2 + a3);
        }
        ls += __shfl_xor(ls, 32);
        l_i += ls;

        uint32_t w[2][8];
#pragma unroll
        for (int mt = 0; mt < 2; mt++)
#pragma unroll
            for (int i = 0; i < 8; i++) {
                union { __bf16 hh[2]; uint32_t u; } pk;
                pk.hh[0] = (__bf16)sf[mt][2 * i];
                pk.hh[1] = (__bf16)sf[mt][2 * i + 1];
                w[mt][i] = pk.u;
            }

#pragma unroll
        for (int ks = 0; ks < 4; ks++) {
            const int cc = 4 * (ks & 1);
            const int mt = ks >> 1;
            u32x2 r1 = __builtin_amdgcn_permlane32_swap(
                w[mt][cc + 0], w[mt][cc + 2], false, false);
            u32x2 r2 = __builtin_amdgcn_permlane32_swap(
                w[mt][cc + 1], w[mt][cc + 3], false, false);
            union { uint32_t u[4]; bf16x8 v8; } pbu;
            pbu.u[0] = r1[0]; pbu.u[1] = r2[0];
            pbu.u[2] = r1[1]; pbu.u[3] = r2[1];
#pragma unroll
            for (int mo = 0; mo < 2; mo++) {
                bf16x8 va = *(const bf16x8*)
                    &Vt[cur][(mo * 32 + l31) * LS + ks * 16 + hi * 8];
                o_acc[mo] = __builtin_amdgcn_mfma_f32_32x32x16_bf16(
                    va, pbu.v8, o_acc[mo], 0, 0, 0);
            }
        }

        __syncthreads();
    }

    {
        const float invl = 1.0f / l_i;
        const size_t orow =
            ((size_t)b * N_ + q0 + wave * 32 + l31) * E_ + h * D_;
#pragma unroll
        for (int mo = 0; mo < 2; mo++)
#pragma unroll
            for (int g = 0; g < 4; g++) {
                union { __bf16 hh[4]; uint2 u2; } pk;
#pragma unroll
                for (int jj = 0; jj < 4; jj++)
                    pk.hh[jj] = (__bf16)(o_acc[mo][4 * g + jj] * invl);
                *(uint2*)&o[orow + mo * 32 + 8 * g + 4 * hi] = pk.u2;
            }
    }
}

// ---------------------------------------------------------------------------
// ws (big): q|k|v|ao (bf16 8.4M each) | Wb (4x1M) | xb0..2 (8.4M each).
// xb region (50.3 MB) is reused for attn partials after the proj GEMM:
//   op: 2560 chunks x 128 x 64 bf16 = 41.94 MB ; ml: 2560x128 float2 = 2.6 MB
// ---------------------------------------------------------------------------
extern "C" void kernel_launch(void* const* d_in, const int* in_sizes, int n_in,
                              void* d_out, int out_size, void* d_ws, size_t ws_size,
                              hipStream_t stream) {
    const float* xq = (const float*)d_in[0];
    const float* xk = (const float*)d_in[1];
    const float* xv = (const float*)d_in[2];
    const float* Wq = (const float*)d_in[4];
    const float* Wk = (const float*)d_in[5];
    const float* Wv = (const float*)d_in[6];
    const float* Wo = (const float*)d_in[7];
    const float* bo = (const float*)d_in[8];
    float* out = (float*)d_out;

    const size_t elems = (size_t)B_ * N_ * E_;   // 8388608
    const size_t wel   = (size_t)E_ * E_;        // 1048576
    bf16* q   = (bf16*)d_ws;
    bf16* kk  = q + elems;
    bf16* vv  = kk + elems;
    bf16* ao  = vv + elems;
    bf16* Wb  = ao + elems;
    bf16* xb0 = Wb + 4 * wel;
    bf16* xb1 = xb0 + elems;
    bf16* xb2 = xb1 + elems;

    const size_t need_big = (7 * elems + 4 * wel) * 2;
    const bool big = ws_size >= need_big;

    dim3 blk(256);
    if (big) {
        cvt_all<<<dim3(14336), blk, 0, stream>>>(
            Wq, Wk, Wv, Wo, Wb, xq, xk, xv, xb0, xb1, xb2);
    } else {
        cvt_all<<<dim3(2048), blk, 0, stream>>>(
            Wq, Wk, Wv, Wo, Wb, nullptr, nullptr, nullptr,
            nullptr, nullptr, nullptr);
    }

    GemmB proj;
    if (big) { proj.A[0] = xb0; proj.A[1] = xb1; proj.A[2] = xb2; }
    else     { proj.A[0] = xq;  proj.A[1] = xk;  proj.A[2] = xv;  }
    proj.C[0] = q; proj.C[1] = kk; proj.C[2] = vv;
    if (big)
        gemm_bt<bf16, bf16><<<dim3(E_ / 128, (B_ * N_) / 128, 3), blk, 0, stream>>>(
            proj, Wb, nullptr);
    else
        gemm_bt<float, bf16><<<dim3(E_ / 128, (B_ * N_) / 128, 3), blk, 0, stream>>>(
            proj, Wb, nullptr);

    if (big) {
        // split-K attention: partials into the (now free) xb region
        bf16*   op = xb0;                                   // 41.94 MB
        float2* ml = (float2*)(xb0 + (size_t)2560 * 8192);  //  2.62 MB
        attn_part<<<dim3(2560), blk, 0, stream>>>(q, kk, vv, op, ml);
        attn_comb<<<dim3(1024), blk, 0, stream>>>(op, ml, ao);
    } else {
        attn_fwd<<<dim3(1024), blk, 0, stream>>>(q, kk, vv, ao);
    }

    GemmB fin;
    fin.A[0] = ao; fin.A[1] = ao; fin.A[2] = ao;
    fin.C[0] = out; fin.C[1] = out; fin.C[2] = out;
    gemm_bt<bf16, float><<<dim3(E_ / 128, (B_ * N_) / 128, 1), blk, 0, stream>>>(
        fin, Wb + 3 * wel, bo);
}

// Round 7
// 337.209 us; speedup vs baseline: 1.0747x; 1.0747x over previous
//
#include <hip/hip_runtime.h>
#include <hip/hip_bf16.h>
#include <stdint.h>
#include <stddef.h>

// Problem constants (fixed by the reference)
#define B_ 4
#define N_ 2048
#define E_ 1024
#define H_ 16
#define D_ 64
// SCALE = 1/sqrt(64) = 0.125 exactly (applied by pre-scaling Q, exact in bf16)

using bf16 = __hip_bfloat16;
typedef __bf16 bf16x8 __attribute__((ext_vector_type(8)));   // 4 VGPRs, MFMA A/B frag
typedef float  f32x4  __attribute__((ext_vector_type(4)));
typedef float  f32x16 __attribute__((ext_vector_type(16)));  // MFMA C/D frag (32x32)
typedef unsigned int u32x2 __attribute__((ext_vector_type(2)));

// ---- dtype helpers --------------------------------------------------------
__device__ inline bf16x8 load8(const float* p) {
    f32x4 a = *(const f32x4*)p;
    f32x4 b = *(const f32x4*)(p + 4);
    bf16x8 r;
#pragma unroll
    for (int e = 0; e < 4; e++) { r[e] = (__bf16)a[e]; r[e + 4] = (__bf16)b[e]; }
    return r;
}
__device__ inline void store_elem(float* C, size_t idx, float v) { C[idx] = v; }
__device__ inline void store_elem(bf16* C, size_t idx, float v) {
    C[idx] = __float2bfloat16(v);
}

// Async global->LDS, 16 B per lane (LDS dest = wave-uniform base + lane*16).
__device__ inline void async_stage16(const bf16* g, bf16* l) {
    __builtin_amdgcn_global_load_lds(
        (const __attribute__((address_space(1))) uint32_t*)g,
        (__attribute__((address_space(3))) uint32_t*)l, 16, 0, 0);
}
__device__ inline void manual_stage16(const float* g, bf16* l) {
    *(bf16x8*)l = load8(g);
}

// ---------------------------------------------------------------------------
// fp32 -> bf16 convert. Blocks 0..2047: weights (512 each); blocks
// 2048..14335: the 3 inputs (4096 each).
// ---------------------------------------------------------------------------
__global__ __launch_bounds__(256) void cvt_all(
    const float* __restrict__ w0, const float* __restrict__ w1,
    const float* __restrict__ w2, const float* __restrict__ w3,
    bf16* __restrict__ wd,
    const float* __restrict__ x0, const float* __restrict__ x1,
    const float* __restrict__ x2,
    bf16* __restrict__ xd0, bf16* __restrict__ xd1, bf16* __restrict__ xd2)
{
    int bx = blockIdx.x;
    const float* s; bf16* d;
    if (bx < 2048) {
        const int seg = bx >> 9;
        s = seg == 0 ? w0 : seg == 1 ? w1 : seg == 2 ? w2 : w3;
        d = wd + (size_t)seg * (E_ * E_);
        bx &= 511;
    } else {
        bx -= 2048;
        const int seg = bx >> 12;
        s = seg == 0 ? x0 : seg == 1 ? x1 : x2;
        d = seg == 0 ? xd0 : seg == 1 ? xd1 : xd2;
        bx &= 4095;
    }
    const size_t off = ((size_t)bx * 256 + threadIdx.x) * 8;
    *(bf16x8*)&d[off] = load8(s + off);
}

// ---------------------------------------------------------------------------
// GEMM: C[M,E] = A[M,E] @ W[E,E]^T (+ optional fp32 bias), fp32 accumulate,
// v_mfma_f32_16x16x32_bf16, 128x128 tile, BK=32, 4 waves; batched blockIdx.z.
//
// Round-13: XCD-locality tile remap. Dispatch linear id = bx + 8*by ->
// XCD = id%8 (round-robin model, validated by attn rounds 10/12 FETCH
// drops). OLD mapping put one W-column x 64 DISTINCT A-panels on each XCD
// (16 MB distinct A through a 4 MB L2: zero A reuse, every staging load on
// the L3 path). NEW: m_tile = xcd*8 + (rr&7), n_tile = rr>>3 -> each XCD
// owns an 8-m-tile A band (2 MB) x all 8 W-columns (2 MB) = 4 MB, exactly
// L2-resident. Bijective: id = ((n_tile*8 + m_tile%8) << 3) | (m_tile/8).
// ---------------------------------------------------------------------------
struct GemmB { const void* A[3]; void* C[3]; };

template <typename TA, typename TC>
__global__ __launch_bounds__(256) void gemm_bt(
    GemmB batch, const bf16* __restrict__ Wb, const float* __restrict__ bias)
{
    __shared__ bf16 As[128 * 32];
    __shared__ bf16 Bs[128 * 32];

    const TA*   __restrict__ A = (const TA*)batch.A[blockIdx.z];
    TC*         __restrict__ C = (TC*)batch.C[blockIdx.z];
    const bf16* __restrict__ W = Wb + (size_t)blockIdx.z * (E_ * E_);

    const int tid  = threadIdx.x;
    const int lane = tid & 63;
    const int wave = tid >> 6;
    const int wr   = wave >> 1;
    const int wc   = wave & 1;
    const int r    = lane & 15;
    const int quad = lane >> 4;

    // XCD-locality remap (grid is (8, 64, z); id%8 tracks the XCD)
    const int id   = blockIdx.x + 8 * blockIdx.y;   // 0..511
    const int xcd  = id & 7;
    const int rr   = id >> 3;                       // 0..63
    const int m0 = (xcd * 8 + (rr & 7)) * 128;      // m_tile 0..63
    const int n0 = (rr >> 3) * 128;                 // n_tile 0..7

    const int row0 = tid >> 2,         cc0 = (tid & 3) * 8;
    const int row1 = (tid + 256) >> 2, cc1 = cc0;

    f32x4 acc[4][4];
#pragma unroll
    for (int i = 0; i < 4; i++)
#pragma unroll
        for (int j = 0; j < 4; j++)
            acc[i][j] = {0.0f, 0.0f, 0.0f, 0.0f};

    for (int k0 = 0; k0 < E_; k0 += 32) {
        __syncthreads();
        if constexpr (__is_same(TA, bf16)) {
            async_stage16(&A[(size_t)(m0 + row0) * E_ + k0 + cc0], &As[tid * 8]);
            async_stage16(&A[(size_t)(m0 + row1) * E_ + k0 + cc1], &As[(tid + 256) * 8]);
        } else {
            manual_stage16(&A[(size_t)(m0 + row0) * E_ + k0 + cc0], &As[tid * 8]);
            manual_stage16(&A[(size_t)(m0 + row1) * E_ + k0 + cc1], &As[(tid + 256) * 8]);
        }
        async_stage16(&W[(size_t)(n0 + row0) * E_ + k0 + cc0], &Bs[tid * 8]);
        async_stage16(&W[(size_t)(n0 + row1) * E_ + k0 + cc1], &Bs[(tid + 256) * 8]);
        __syncthreads();

        bf16x8 a[4], b[4];
#pragma unroll
        for (int mt = 0; mt < 4; mt++)
            a[mt] = *(const bf16x8*)&As[(wr * 64 + mt * 16 + r) * 32 + quad * 8];
#pragma unroll
        for (int nt = 0; nt < 4; nt++)
            b[nt] = *(const bf16x8*)&Bs[(wc * 64 + nt * 16 + r) * 32 + quad * 8];
#pragma unroll
        for (int mt = 0; mt < 4; mt++)
#pragma unroll
            for (int nt = 0; nt < 4; nt++)
                acc[mt][nt] = __builtin_amdgcn_mfma_f32_16x16x32_bf16(
                    a[mt], b[nt], acc[mt][nt], 0, 0, 0);
    }

#pragma unroll
    for (int mt = 0; mt < 4; mt++) {
#pragma unroll
        for (int nt = 0; nt < 4; nt++) {
            const int col = n0 + wc * 64 + nt * 16 + r;
            float bv = bias ? bias[col] : 0.0f;
#pragma unroll
            for (int rg = 0; rg < 4; rg++) {
                const int row = m0 + wr * 64 + mt * 16 + quad * 4 + rg;
                store_elem(C, (size_t)row * E_ + col, acc[mt][nt][rg] + bv);
            }
        }
    }
}

// ---------------------------------------------------------------------------
// MFMA flash attention, round-13 (= round-11 verbatim; split-K reverted).
//
// Round-12 evidence: 8-tile chunks gave IDENTICAL 98.5us -> throughput-
// limited (~1.4 us/tile/CU), not makespan-limited; split-K only added
// combine-pass + 88 MB partial traffic. Counters are chip-real (MfmaUtil
// 15% == measured 373 TF): VALUBusy ~71% is the dominant pipe. r11 kernel
// is the best measured single-pass (98.2us): grid 1024, one strip/block,
// balanced slot mapping (CU strip-sums == 30), bh%8 == l%8 L2 locality
// (FETCH 25 MB, verified), 32x32x16 S^T/PV, in-register P via
// cvt_pk+permlane32_swap, defer-max THR=8, exp2 domain.
// ---------------------------------------------------------------------------
__global__ __launch_bounds__(256) void attn_fwd(
    const bf16* __restrict__ q, const bf16* __restrict__ k,
    const bf16* __restrict__ v, bf16* __restrict__ o)
{
    constexpr int LS = 72;
    constexpr float LOG2E = 1.44269504088896340736f;
    __shared__ bf16 Ks[2][64 * LS];   // [buf][key][d]
    __shared__ bf16 Vt[2][64 * LS];   // [buf][d][key]

    const int tid  = threadIdx.x;
    const int lane = tid & 63;
    const int wave = tid >> 6;
    const int l31  = lane & 31;
    const int hi   = lane >> 5;

    // Balanced XCD-locality mapping.
    const int l    = blockIdx.x;         // 0..1023
    const int xcd  = l & 7;
    const int j    = l >> 3;             // 0..127
    const int bh_hi= j & 7;
    const int a    = (j >> 3) & 3;
    const int slot = j >> 5;             // 0..3
    const int s    = 4 * slot + (a ^ slot);  // strip 0..15
    const int bh   = (bh_hi << 3) | xcd;
    const int b    = bh >> 4;
    const int h    = bh & 15;

    const size_t basek = (size_t)b * N_ * E_ + (size_t)h * D_;

    // staging addressing
    const int key0 = tid >> 3;        // 0..31
    const int key1 = key0 + 32;
    const int ck   = (tid & 7) * 8;
    const int kp   = tid & 31;
    const int cv   = (tid >> 5) * 8;

    const int q0 = s * 128;
    const int nt = 2 * s + 2;         // key tiles 0..nt-1 (keys 0..q0+127)

    // Q as B-operand of 32x32x16: B[k=hi*8+e][col=qrow=l31], kc selects
    // which 16 of D=64. Pre-scaled by 0.125 (exact in bf16).
    bf16x8 qB[4];
    {
        const size_t qoff =
            ((size_t)b * N_ + q0 + wave * 32 + l31) * E_ + h * D_ + hi * 8;
#pragma unroll
        for (int kc = 0; kc < 4; kc++) {
            qB[kc] = *(const bf16x8*)&q[qoff + kc * 16];
#pragma unroll
            for (int e = 0; e < 8; e++)
                qB[kc][e] = (__bf16)((float)qB[kc][e] * 0.125f);
        }
    }

    float m_i = -1e30f;
    float l_i = 0.0f;
    f32x16 o_acc[2];              // O^T C-layout: col=qrow, row=d half
#pragma unroll
    for (int rg = 0; rg < 16; rg++) { o_acc[0][rg] = 0.0f; o_acc[1][rg] = 0.0f; }

    // ---- prologue: tile 0 -> buf0; issue loads for tile 1 ----
    bf16x8 kp0, kp1, vp0, vp1;
    kp0 = *(const bf16x8*)&k[basek + (size_t)key0 * E_ + ck];
    kp1 = *(const bf16x8*)&k[basek + (size_t)key1 * E_ + ck];
    vp0 = *(const bf16x8*)&v[basek + (size_t)(2 * kp) * E_ + cv];
    vp1 = *(const bf16x8*)&v[basek + (size_t)(2 * kp + 1) * E_ + cv];
    *(bf16x8*)&Ks[0][key0 * LS + ck] = kp0;
    *(bf16x8*)&Ks[0][key1 * LS + ck] = kp1;
#pragma unroll
    for (int e = 0; e < 8; e++) {
        union { __bf16 hh[2]; uint32_t u; } pk;
        pk.hh[0] = vp0[e]; pk.hh[1] = vp1[e];
        *(uint32_t*)&Vt[0][(cv + e) * LS + 2 * kp] = pk.u;
    }
    {
        const size_t j1 = 64;     // tile 1 (nt >= 2 always)
        kp0 = *(const bf16x8*)&k[basek + (j1 + key0) * E_ + ck];
        kp1 = *(const bf16x8*)&k[basek + (j1 + key1) * E_ + ck];
        vp0 = *(const bf16x8*)&v[basek + (j1 + 2 * kp) * E_ + cv];
        vp1 = *(const bf16x8*)&v[basek + (j1 + 2 * kp + 1) * E_ + cv];
    }
    __syncthreads();              // buf0 visible to all waves

    for (int t = 0; t < nt; t++) {
        const int cur = t & 1;

        // ---- commit tile t+1 (regs loaded one tile ago) to other buf ----
        if (t + 1 < nt) {
            *(bf16x8*)&Ks[cur ^ 1][key0 * LS + ck] = kp0;
            *(bf16x8*)&Ks[cur ^ 1][key1 * LS + ck] = kp1;
#pragma unroll
            for (int e = 0; e < 8; e++) {
                union { __bf16 hh[2]; uint32_t u; } pk;
                pk.hh[0] = vp0[e]; pk.hh[1] = vp1[e];
                *(uint32_t*)&Vt[cur ^ 1][(cv + e) * LS + 2 * kp] = pk.u;
            }
        }
        // ---- issue loads for tile t+2 (AFTER commit, so commit's vmcnt
        //      wait doesn't include them) ----
        if (t + 2 < nt) {
            const size_t j2 = (size_t)(t + 2) * 64;
            kp0 = *(const bf16x8*)&k[basek + (j2 + key0) * E_ + ck];
            kp1 = *(const bf16x8*)&k[basek + (j2 + key1) * E_ + ck];
            vp0 = *(const bf16x8*)&v[basek + (j2 + 2 * kp) * E_ + cv];
            vp1 = *(const bf16x8*)&v[basek + (j2 + 2 * kp + 1) * E_ + cv];
        }

        // ---- S^T[key][qrow] = K·(scaled Q)^T : 8 MFMA 32x32x16 ----
        f32x16 sf[2];
#pragma unroll
        for (int rg = 0; rg < 16; rg++) { sf[0][rg] = 0.0f; sf[1][rg] = 0.0f; }
#pragma unroll
        for (int kc = 0; kc < 4; kc++) {
            bf16x8 ka0 = *(const bf16x8*)&Ks[cur][l31 * LS + kc * 16 + hi * 8];
            bf16x8 ka1 = *(const bf16x8*)&Ks[cur][(32 + l31) * LS + kc * 16 + hi * 8];
            sf[0] = __builtin_amdgcn_mfma_f32_32x32x16_bf16(ka0, qB[kc], sf[0], 0, 0, 0);
            sf[1] = __builtin_amdgcn_mfma_f32_32x32x16_bf16(ka1, qB[kc], sf[1], 0, 0, 0);
        }

        // ---- causal mask (only last 2 tiles of the strip) ----
        // key = mt*32 + (rg&3) + 8*(rg>>2) + 4*hi ; qrow = l31
        if (t >= nt - 2) {
            const int qgl   = q0 + wave * 32 + l31;
            const int kbase = t * 64 + 4 * hi;
#pragma unroll
            for (int mt = 0; mt < 2; mt++)
#pragma unroll
                for (int rg = 0; rg < 16; rg++) {
                    const int kgl = kbase + mt * 32 + (rg & 3) + 8 * (rg >> 2);
                    if (kgl > qgl) sf[mt][rg] = -1e30f;
                }
        }

        // ---- online softmax: each lane owns half its q-row; partner
        //      lane (l^32) owns the other half ----
        float mhalf[8];
#pragma unroll
        for (int i = 0; i < 8; i++)
            mhalf[i] = fmaxf(fmaxf(sf[0][2 * i], sf[0][2 * i + 1]),
                             fmaxf(sf[1][2 * i], sf[1][2 * i + 1]));
        float mx = fmaxf(fmaxf(fmaxf(mhalf[0], mhalf[1]), fmaxf(mhalf[2], mhalf[3])),
                         fmaxf(fmaxf(mhalf[4], mhalf[5]), fmaxf(mhalf[6], mhalf[7])));
        mx = fmaxf(mx, __shfl_xor(mx, 32));

        // defer-max (THR=8): rescale only when the running max really grew
        if (!__all(mx <= m_i + 8.0f)) {
            const float m_new = fmaxf(m_i, mx);
            const float al = exp2f((m_i - m_new) * LOG2E);
            l_i *= al;
#pragma unroll
            for (int mo = 0; mo < 2; mo++)
#pragma unroll
                for (int rg = 0; rg < 16; rg++) o_acc[mo][rg] *= al;
            m_i = m_new;
        }

        const float m2 = m_i * LOG2E;
#pragma unroll
        for (int mt = 0; mt < 2; mt++)
#pragma unroll
            for (int rg = 0; rg < 16; rg++)
                sf[mt][rg] = exp2f(__builtin_fmaf(sf[mt][rg], LOG2E, -m2));

        float ls = 0.0f;
#pragma unroll
        for (int mt = 0; mt < 2; mt++) {
            const float a0 = (sf[mt][0] + sf[mt][1]) + (sf[mt][2] + sf[mt][3]);
            const float a1 = (sf[mt][4] + sf[mt][5]) + (sf[mt][6] + sf[mt][7]);
            const float a2 = (sf[mt][8] + sf[mt][9]) + (sf[mt][10] + sf[mt][11]);
            const float a3 = (sf[mt][12] + sf[mt][13]) + (sf[mt][14] + sf[mt][15]);
            ls += (a0 + a1) + (a2 + a3);
        }
        ls += __shfl_xor(ls, 32);
        l_i += ls;

        // ---- pack P to bf16 pair-words (v_cvt_pk_bf16_f32) ----
        uint32_t w[2][8];
#pragma unroll
        for (int mt = 0; mt < 2; mt++)
#pragma unroll
            for (int i = 0; i < 8; i++) {
                union { __bf16 hh[2]; uint32_t u; } pk;
                pk.hh[0] = (__bf16)sf[mt][2 * i];
                pk.hh[1] = (__bf16)sf[mt][2 * i + 1];
                w[mt][i] = pk.u;
            }

        // ---- O^T += V^T · P^T : PV B-frags via permlane32_swap ----
        // r1 = swap(w[c], w[c+2]) -> m0 = r1[0], m2 = r1[1] (both halves)
        // r2 = swap(w[c+1], w[c+3]) -> m1 = r2[0], m3 = r2[1]
#pragma unroll
        for (int ks = 0; ks < 4; ks++) {
            const int c  = 4 * (ks & 1);
            const int mt = ks >> 1;
            u32x2 r1 = __builtin_amdgcn_permlane32_swap(
                w[mt][c + 0], w[mt][c + 2], false, false);
            u32x2 r2 = __builtin_amdgcn_permlane32_swap(
                w[mt][c + 1], w[mt][c + 3], false, false);
            union { uint32_t u[4]; bf16x8 v8; } pbu;
            pbu.u[0] = r1[0]; pbu.u[1] = r2[0];
            pbu.u[2] = r1[1]; pbu.u[3] = r2[1];
#pragma unroll
            for (int mo = 0; mo < 2; mo++) {
                bf16x8 va = *(const bf16x8*)
                    &Vt[cur][(mo * 32 + l31) * LS + ks * 16 + hi * 8];
                o_acc[mo] = __builtin_amdgcn_mfma_f32_32x32x16_bf16(
                    va, pbu.v8, o_acc[mo], 0, 0, 0);
            }
        }

        __syncthreads();   // buf[cur] free for next commit; buf[cur^1] visible
    }

    // ---- normalize + store (O^T: col=qrow=l31, row=d) ----
    {
        const float invl = 1.0f / l_i;
        const size_t orow =
            ((size_t)b * N_ + q0 + wave * 32 + l31) * E_ + h * D_;
#pragma unroll
        for (int mo = 0; mo < 2; mo++)
#pragma unroll
            for (int g = 0; g < 4; g++) {
                union { __bf16 hh[4]; uint2 u2; } pk;
#pragma unroll
                for (int jj = 0; jj < 4; jj++)
                    pk.hh[jj] = (__bf16)(o_acc[mo][4 * g + jj] * invl);
                *(uint2*)&o[orow + mo * 32 + 8 * g + 4 * hi] = pk.u2;
            }
    }
}

// ---------------------------------------------------------------------------
// Inputs: xq, xk, xv, attn_mask, Wq, Wk, Wv, Wo, bo (all fp32; mask structural)
// ws (big): q|k|v|ao (bf16 8.4M each) | Wb (4x1M) | xb0..2 (8.4M each) =126 MB
// ws (small fallback): first 75.5 MB only; proj GEMM stages fp32 A manually.
// ---------------------------------------------------------------------------
extern "C" void kernel_launch(void* const* d_in, const int* in_sizes, int n_in,
                              void* d_out, int out_size, void* d_ws, size_t ws_size,
                              hipStream_t stream) {
    const float* xq = (const float*)d_in[0];
    const float* xk = (const float*)d_in[1];
    const float* xv = (const float*)d_in[2];
    const float* Wq = (const float*)d_in[4];
    const float* Wk = (const float*)d_in[5];
    const float* Wv = (const float*)d_in[6];
    const float* Wo = (const float*)d_in[7];
    const float* bo = (const float*)d_in[8];
    float* out = (float*)d_out;

    const size_t elems = (size_t)B_ * N_ * E_;   // 8388608
    const size_t wel   = (size_t)E_ * E_;        // 1048576
    bf16* q   = (bf16*)d_ws;
    bf16* kk  = q + elems;
    bf16* vv  = kk + elems;
    bf16* ao  = vv + elems;
    bf16* Wb  = ao + elems;
    bf16* xb0 = Wb + 4 * wel;
    bf16* xb1 = xb0 + elems;
    bf16* xb2 = xb1 + elems;

    const size_t need_big = (7 * elems + 4 * wel) * 2;
    const bool big = ws_size >= need_big;

    dim3 blk(256);
    if (big) {
        cvt_all<<<dim3(14336), blk, 0, stream>>>(
            Wq, Wk, Wv, Wo, Wb, xq, xk, xv, xb0, xb1, xb2);
    } else {
        cvt_all<<<dim3(2048), blk, 0, stream>>>(
            Wq, Wk, Wv, Wo, Wb, nullptr, nullptr, nullptr,
            nullptr, nullptr, nullptr);
    }

    GemmB proj;
    if (big) { proj.A[0] = xb0; proj.A[1] = xb1; proj.A[2] = xb2; }
    else     { proj.A[0] = xq;  proj.A[1] = xk;  proj.A[2] = xv;  }
    proj.C[0] = q; proj.C[1] = kk; proj.C[2] = vv;
    if (big)
        gemm_bt<bf16, bf16><<<dim3(E_ / 128, (B_ * N_) / 128, 3), blk, 0, stream>>>(
            proj, Wb, nullptr);
    else
        gemm_bt<float, bf16><<<dim3(E_ / 128, (B_ * N_) / 128, 3), blk, 0, stream>>>(
            proj, Wb, nullptr);

    attn_fwd<<<dim3(1024), blk, 0, stream>>>(q, kk, vv, ao);

    GemmB fin;
    fin.A[0] = ao; fin.A[1] = ao; fin.A[2] = ao;
    fin.C[0] = out; fin.C[1] = out; fin.C[2] = out;
    gemm_bt<bf16, float><<<dim3(E_ / 128, (B_ * N_) / 128, 1), blk, 0, stream>>>(
        fin, Wb + 3 * wel, bo);
}